// Round 1
// baseline (1240.989 us; speedup 1.0000x reference)
//
#include <hip/hip_runtime.h>

#define B_  16
#define C_  256
#define H_  64
#define W_  64
#define K_  4
#define OC_ 64
#define O_  256   // 4 rotations * OC
#define F_  3

// conv tiling
#define OT 16     // o-channels per block (stays within one rotation: 16 | 64)
#define RT 16     // output rows per block
#define CB 4      // input channels per LDS chunk

// ---------------------------------------------------------------- pool ------
__global__ __launch_bounds__(256) void pool_kernel(const float* __restrict__ x,
                                                   float* __restrict__ pooled) {
    int bc = blockIdx.x;                       // (b*C + c), 4096 blocks
    const float4* p = (const float4*)(x + (size_t)bc * (H_ * W_));
    float s = 0.f;
#pragma unroll
    for (int i = 0; i < 4; ++i) {              // 1024 float4 / 256 threads
        float4 v = p[threadIdx.x + 256 * i];
        s += v.x + v.y + v.z + v.w;
    }
#pragma unroll
    for (int off = 32; off; off >>= 1) s += __shfl_down(s, off, 64);
    __shared__ float red[4];
    int lane = threadIdx.x & 63, wid = threadIdx.x >> 6;
    if (lane == 0) red[wid] = s;
    __syncthreads();
    if (threadIdx.x == 0)
        pooled[bc] = (red[0] + red[1] + red[2] + red[3]) * (1.0f / (H_ * W_));
}

// ---------------------------------------------------------------- coeffs ----
__global__ __launch_bounds__(64) void coeffs_kernel(const float* __restrict__ pooled,
                                                    const float* __restrict__ W_fc,
                                                    const float* __restrict__ b_fc,
                                                    float* __restrict__ coeffs) {
    __shared__ float logits[B_][K_];
    int t = threadIdx.x;
    if (t < B_ * K_) {
        int b = t / K_, k = t % K_;
        float s = b_fc[k];
        for (int c = 0; c < C_; ++c) s += pooled[b * C_ + c] * W_fc[k * C_ + c];
        logits[b][k] = s;
    }
    __syncthreads();
    if (t < B_) {
        float m = logits[t][0];
        for (int k = 1; k < K_; ++k) m = fmaxf(m, logits[t][k]);
        float e[K_], sum = 0.f;
        for (int k = 0; k < K_; ++k) { e[k] = expf(logits[t][k] - m); sum += e[k]; }
        for (int k = 0; k < K_; ++k) coeffs[t * K_ + k] = e[k] / sum;
    }
}

// ---------------------------------------------------------------- conv ------
// grid: (row_tile=4, o_tile=16, b=16), block 256.
// Each block: 16 o (one rotation) x 16 rows x 64 cols.
// Thread t: row = t>>4, cols 4*(t&15)..+3, all 16 o -> 64 fp32 accumulators.
__global__ __launch_bounds__(256) void conv_kernel(const float* __restrict__ x,
                                                   const float* __restrict__ bank,
                                                   const float* __restrict__ coeffs,
                                                   float* __restrict__ out) {
    const int rt = blockIdx.x;            // 0..3
    const int ot = blockIdx.y;            // 0..15
    const int b  = blockIdx.z;            // 0..15

    const int o_base   = ot * OT;         // 0..240
    const int rot      = o_base / OC_;    // rotation index 0..3 (uniform in block)
    const int oc_base  = o_base % OC_;
    const int y0       = rt * RT;

    const int t   = threadIdx.x;
    const int row = t >> 4;               // 0..15
    const int cg  = t & 15;               // col group: cols 4*cg..4*cg+3

    // stride W_+3=67: 67 mod 32 = 3 -> consecutive rows land on shifted banks
    __shared__ float xs[CB][RT + 2][W_ + 3];
    __shared__ float wsm[CB][F_][F_][OT];

    const float c0v = coeffs[b * K_ + 0];
    const float c1v = coeffs[b * K_ + 1];
    const float c2v = coeffs[b * K_ + 2];
    const float c3v = coeffs[b * K_ + 3];

    float acc[OT][4];
#pragma unroll
    for (int o = 0; o < OT; ++o)
#pragma unroll
        for (int p = 0; p < 4; ++p) acc[o][p] = 0.f;

    for (int c0 = 0; c0 < C_; c0 += CB) {
        __syncthreads();
        // ---- stage x tile: CB x (RT+2) x (W+2), zero-padded halo
        for (int idx = t; idx < CB * (RT + 2) * (W_ + 2); idx += 256) {
            int cc   = idx % (W_ + 2);
            int rest = idx / (W_ + 2);
            int rr   = rest % (RT + 2);
            int cl   = rest / (RT + 2);
            int gy = y0 + rr - 1;
            int gx = cc - 1;
            float v = 0.f;
            if ((unsigned)gy < H_ && (unsigned)gx < W_)
                v = x[(((size_t)b * C_ + (c0 + cl)) * H_ + gy) * W_ + gx];
            xs[cl][rr][cc] = v;
        }
        // ---- stage mixed+rotated weights: CB x 3 x 3 x OT
        for (int idx = t; idx < CB * 9 * OT; idx += 256) {
            int ol   = idx % OT;
            int rest = idx / OT;
            int j  = rest % 3;
            int i  = (rest / 3) % 3;
            int cl = rest / 9;
            // w[i][j] = base[si][sj], rot90 applied `rot` times
            int si, sj;
            if      (rot == 0) { si = i;     sj = j;     }
            else if (rot == 1) { si = j;     sj = 2 - i; }
            else if (rot == 2) { si = 2 - i; sj = 2 - j; }
            else               { si = 2 - j; sj = i;     }
            int oc = oc_base + ol;
            size_t bi = ((size_t)oc * C_ + (c0 + cl)) * 9 + si * 3 + sj;
            const size_t kstride = (size_t)OC_ * C_ * 9;
            float w = c0v * bank[bi]
                    + c1v * bank[bi + kstride]
                    + c2v * bank[bi + 2 * kstride]
                    + c3v * bank[bi + 3 * kstride];
            wsm[cl][i][j][ol] = w;
        }
        __syncthreads();
        // ---- compute
#pragma unroll 1
        for (int cl = 0; cl < CB; ++cl) {
#pragma unroll
            for (int i = 0; i < F_; ++i)
#pragma unroll
                for (int j = 0; j < F_; ++j) {
                    float xv0 = xs[cl][row + i][4 * cg + 0 + j];
                    float xv1 = xs[cl][row + i][4 * cg + 1 + j];
                    float xv2 = xs[cl][row + i][4 * cg + 2 + j];
                    float xv3 = xs[cl][row + i][4 * cg + 3 + j];
#pragma unroll
                    for (int o = 0; o < OT; ++o) {
                        float wv = wsm[cl][i][j][o];
                        acc[o][0] = fmaf(xv0, wv, acc[o][0]);
                        acc[o][1] = fmaf(xv1, wv, acc[o][1]);
                        acc[o][2] = fmaf(xv2, wv, acc[o][2]);
                        acc[o][3] = fmaf(xv3, wv, acc[o][3]);
                    }
                }
        }
    }

    // ---- write out: coalesced float4 per (o, row)
    const int y = y0 + row;
#pragma unroll
    for (int o = 0; o < OT; ++o) {
        float4 v = make_float4(acc[o][0], acc[o][1], acc[o][2], acc[o][3]);
        *(float4*)&out[(((size_t)b * O_ + (o_base + o)) * H_ + y) * W_ + 4 * cg] = v;
    }
}

// ---------------------------------------------------------------- launch ----
extern "C" void kernel_launch(void* const* d_in, const int* in_sizes, int n_in,
                              void* d_out, int out_size, void* d_ws, size_t ws_size,
                              hipStream_t stream) {
    const float* x     = (const float*)d_in[0];
    const float* W_fc  = (const float*)d_in[1];
    const float* b_fc  = (const float*)d_in[2];
    const float* bank  = (const float*)d_in[3];
    float* out = (float*)d_out;

    float* pooled = (float*)d_ws;              // B*C floats
    float* coeffs = pooled + B_ * C_;          // B*K floats

    pool_kernel<<<B_ * C_, 256, 0, stream>>>(x, pooled);
    coeffs_kernel<<<1, 64, 0, stream>>>(pooled, W_fc, b_fc, coeffs);

    dim3 grid(H_ / RT, O_ / OT, B_);
    conv_kernel<<<grid, 256, 0, stream>>>(x, bank, coeffs, out);
}

// Round 2
// 167.166 us; speedup vs baseline: 7.4237x; 7.4237x over previous
//
#include <hip/hip_runtime.h>

#define B_   16
#define C_   256
#define H_   64
#define W_   64
#define K_   4
#define OC_  64
#define O_   256
#define NTAP 9

typedef short  short4v __attribute__((ext_vector_type(4)));
typedef short  bf16x8  __attribute__((ext_vector_type(8)));
typedef float  f32x16  __attribute__((ext_vector_type(16)));

#define WOR_ELEMS (B_ * NTAP * O_ * C_)      // bf16 elems
#define WOR_BYTES (WOR_ELEMS * 2)            // 18,874,368 B

// channel-slot stride in shorts (16 data + 4 pad -> 40 B, bank period 16)
#define CSTR 20

__device__ __forceinline__ short f2bf(float f) {
    unsigned u = __float_as_uint(f);
    u += 0x7fffu + ((u >> 16) & 1u);         // RNE
    return (short)(u >> 16);
}

__device__ __forceinline__ bf16x8 load8(const short* p) {
    union { bf16x8 v; short4v h[2]; } u;
    u.h[0] = *(const short4v*)p;
    u.h[1] = *(const short4v*)(p + 4);
    return u.v;
}

// ---------------------------------------------------------------- pool ------
__global__ __launch_bounds__(256) void pool_kernel(const float* __restrict__ x,
                                                   float* __restrict__ pooled) {
    int bc = blockIdx.x;
    const float4* p = (const float4*)(x + (size_t)bc * (H_ * W_));
    float s = 0.f;
#pragma unroll
    for (int i = 0; i < 4; ++i) {
        float4 v = p[threadIdx.x + 256 * i];
        s += v.x + v.y + v.z + v.w;
    }
#pragma unroll
    for (int off = 32; off; off >>= 1) s += __shfl_down(s, off, 64);
    __shared__ float red[4];
    int lane = threadIdx.x & 63, wid = threadIdx.x >> 6;
    if (lane == 0) red[wid] = s;
    __syncthreads();
    if (threadIdx.x == 0)
        pooled[bc] = (red[0] + red[1] + red[2] + red[3]) * (1.0f / (H_ * W_));
}

// ---------------------------------------------------------------- coeffs ----
__global__ __launch_bounds__(64) void coeffs_kernel(const float* __restrict__ pooled,
                                                    const float* __restrict__ W_fc,
                                                    const float* __restrict__ b_fc,
                                                    float* __restrict__ coeffs) {
    __shared__ float logits[B_][K_];
    int t = threadIdx.x;
    if (t < B_ * K_) {
        int b = t / K_, k = t % K_;
        float s = b_fc[k];
        for (int c = 0; c < C_; ++c) s += pooled[b * C_ + c] * W_fc[k * C_ + c];
        logits[b][k] = s;
    }
    __syncthreads();
    if (t < B_) {
        float m = logits[t][0];
        for (int k = 1; k < K_; ++k) m = fmaxf(m, logits[t][k]);
        float e[K_], sum = 0.f;
        for (int k = 0; k < K_; ++k) { e[k] = expf(logits[t][k] - m); sum += e[k]; }
        for (int k = 0; k < K_; ++k) coeffs[t * K_ + k] = e[k] / sum;
    }
}

// ---------------------------------------------------------------- mix -------
// w_or[b][tap][o = r*64+oc][c] bf16, c contiguous.
// oriented_r[i][j] = rot90^r(base)[i][j]; given source (si,sj):
//   r=0: tap=(si,sj)  r=1: tap=(2-sj,si)  r=2: tap=(2-si,2-sj)  r=3: tap=(sj,2-si)
__global__ __launch_bounds__(256) void mix_kernel(const float* __restrict__ bank,
                                                  const float* __restrict__ coeffs,
                                                  short* __restrict__ wor) {
    __shared__ float bl[K_][C_ * 9];
    const int b  = blockIdx.x;   // 16
    const int oc = blockIdx.y;   // 64
    const int t  = threadIdx.x;

    for (int k = 0; k < K_; ++k) {
        const float4* src = (const float4*)(bank + ((size_t)k * OC_ + oc) * (C_ * 9));
        for (int idx = t; idx < (C_ * 9) / 4; idx += 256)
            ((float4*)bl[k])[idx] = src[idx];
    }
    const float c0 = coeffs[b * K_ + 0];
    const float c1 = coeffs[b * K_ + 1];
    const float c2 = coeffs[b * K_ + 2];
    const float c3 = coeffs[b * K_ + 3];
    __syncthreads();

    const int c = t;  // 0..255
#pragma unroll
    for (int rep = 0; rep < 9; ++rep) {
        float v = c0 * bl[0][c * 9 + rep] + c1 * bl[1][c * 9 + rep]
                + c2 * bl[2][c * 9 + rep] + c3 * bl[3][c * 9 + rep];
        short hv = f2bf(v);
        int si = rep / 3, sj = rep % 3;
        int t0 = si * 3 + sj;
        int t1 = (2 - sj) * 3 + si;
        int t2 = (2 - si) * 3 + (2 - sj);
        int t3 = sj * 3 + (2 - si);
        wor[(((size_t)b * NTAP + t0) * O_ +   0 + oc) * C_ + c] = hv;
        wor[(((size_t)b * NTAP + t1) * O_ +  64 + oc) * C_ + c] = hv;
        wor[(((size_t)b * NTAP + t2) * O_ + 128 + oc) * C_ + c] = hv;
        wor[(((size_t)b * NTAP + t3) * O_ + 192 + oc) * C_ + c] = hv;
    }
}

// ---------------------------------------------------------------- conv ------
// Block: 128 o x 128 pixels (2 output rows), 4 waves, each 64o x 64px as
// 2x2 frags of 32x32; mfma_f32_32x32x16_bf16, A = weights[o][c], B = x[c][px].
__global__ __launch_bounds__(256, 2) void conv_mfma(const float* __restrict__ x,
                                                    const short* __restrict__ wor,
                                                    float* __restrict__ out) {
    __shared__ short xs[4 * 66 * CSTR];         // [ry][col][c] 10,560 B
    __shared__ short wl[NTAP * 128 * CSTR];     // [tap][o][c]  46,080 B

    const int pt = blockIdx.x;                  // 0..31: 2 output rows
    const int o0 = blockIdx.y * 128;            // 0 or 128
    const int b  = blockIdx.z;
    const int y0 = pt * 2;

    const int t    = threadIdx.x;
    const int lane = t & 63;
    const int wid  = t >> 6;
    const int wm   = wid >> 1;                  // o 64-half
    const int wn   = wid & 1;                   // output row within tile
    const int l31  = lane & 31;
    const int lh   = lane >> 5;

    // zero halo cols (col 0 and 65) once — never overwritten by staging
    if (t < 128) {
        int c  = t & 15;
        int ry = (t >> 4) & 3;
        int col = (t >> 6) ? 65 : 0;
        xs[(ry * 66 + col) * CSTR + c] = 0;
    }

    f32x16 acc00{}, acc01{}, acc10{}, acc11{};

    const int wb0 = (wm * 64 + l31) * CSTR + lh * 8;
    const int wb1 = wb0 + 32 * CSTR;
    const int xb0 = (wn * 66 + l31) * CSTR + lh * 8;
    const int xb1 = xb0 + 32 * CSTR;

    const int sc   = t & 15;                    // staging channel
    const int part = t >> 4;                    // staging col group (4 px)

    for (int c0 = 0; c0 < C_; c0 += 16) {
        __syncthreads();
        // ---- stage x: rows y0-1..y0+2, cols 1..64, 16 channels -> bf16
        {
            const float* xp = x + ((size_t)b * C_ + c0 + sc) * (H_ * W_) + part * 4;
#pragma unroll
            for (int ry = 0; ry < 4; ++ry) {
                int gy = y0 - 1 + ry;
                float4 v = make_float4(0.f, 0.f, 0.f, 0.f);
                if ((unsigned)gy < H_) v = *(const float4*)(xp + gy * W_);
                int base = (ry * 66 + 1 + part * 4) * CSTR + sc;
                xs[base          ] = f2bf(v.x);
                xs[base + CSTR   ] = f2bf(v.y);
                xs[base + 2*CSTR ] = f2bf(v.z);
                xs[base + 3*CSTR ] = f2bf(v.w);
            }
        }
        // ---- stage w: 9 taps x 128 o x 16 c (16B per thread-iter)
#pragma unroll
        for (int r = 0; r < 9; ++r) {
            int idx  = t + 256 * r;
            int half = idx & 1;
            int ol   = (idx >> 1) & 127;
            int tap  = idx >> 8;
            const short* src = wor + (((size_t)(b * NTAP + tap) * O_ + o0 + ol) * C_
                                      + c0 + half * 8);
            float4 d = *(const float4*)src;
            short4v* dst = (short4v*)&wl[tap * (128 * CSTR) + ol * CSTR + half * 8];
            dst[0] = ((const short4v*)&d)[0];
            dst[1] = ((const short4v*)&d)[1];
        }
        __syncthreads();
        // ---- compute: 9 taps x 4 MFMAs
#pragma unroll
        for (int i = 0; i < 3; ++i)
#pragma unroll
            for (int j = 0; j < 3; ++j) {
                const int wo = (i * 3 + j) * (128 * CSTR);
                const int xo = (i * 66 + j) * CSTR;
                bf16x8 wa0 = load8(&wl[wb0 + wo]);
                bf16x8 wa1 = load8(&wl[wb1 + wo]);
                bf16x8 xv0 = load8(&xs[xb0 + xo]);
                bf16x8 xv1 = load8(&xs[xb1 + xo]);
                acc00 = __builtin_amdgcn_mfma_f32_32x32x16_bf16(wa0, xv0, acc00, 0, 0, 0);
                acc01 = __builtin_amdgcn_mfma_f32_32x32x16_bf16(wa0, xv1, acc01, 0, 0, 0);
                acc10 = __builtin_amdgcn_mfma_f32_32x32x16_bf16(wa1, xv0, acc10, 0, 0, 0);
                acc11 = __builtin_amdgcn_mfma_f32_32x32x16_bf16(wa1, xv1, acc11, 0, 0, 0);
            }
    }

    // ---- epilogue: D[o][px]; col=lane&31 -> pixel, row from reg
    const int px_base = pt * 128 + wn * 64 + l31;
    float* outb = out + (size_t)b * O_ * (H_ * W_);
    const int ob = o0 + wm * 64 + 4 * lh;
#pragma unroll
    for (int r = 0; r < 16; ++r) {
        int row = (r & 3) + 8 * (r >> 2);
        outb[((size_t)(ob + row)      << 12) + px_base     ] = acc00[r];
        outb[((size_t)(ob + row)      << 12) + px_base + 32] = acc01[r];
        outb[((size_t)(ob + row + 32) << 12) + px_base     ] = acc10[r];
        outb[((size_t)(ob + row + 32) << 12) + px_base + 32] = acc11[r];
    }
}

// ---------------------------------------------------------------- launch ----
extern "C" void kernel_launch(void* const* d_in, const int* in_sizes, int n_in,
                              void* d_out, int out_size, void* d_ws, size_t ws_size,
                              hipStream_t stream) {
    const float* x    = (const float*)d_in[0];
    const float* W_fc = (const float*)d_in[1];
    const float* b_fc = (const float*)d_in[2];
    const float* bank = (const float*)d_in[3];
    float* out = (float*)d_out;

    short* wor    = (short*)d_ws;
    float* pooled = (float*)((char*)d_ws + WOR_BYTES);
    float* coeffs = pooled + B_ * C_;

    pool_kernel<<<B_ * C_, 256, 0, stream>>>(x, pooled);
    coeffs_kernel<<<1, 64, 0, stream>>>(pooled, W_fc, b_fc, coeffs);
    mix_kernel<<<dim3(B_, OC_), 256, 0, stream>>>(bank, coeffs, wor);

    dim3 grid(32, 2, B_);
    conv_mfma<<<grid, 256, 0, stream>>>(x, wor, out);
}

// Round 3
// 123.537 us; speedup vs baseline: 10.0454x; 1.3532x over previous
//
#include <hip/hip_runtime.h>

#define B_  16
#define C_  256
#define OC_ 64
#define O_  256

typedef short    bf16x8 __attribute__((ext_vector_type(8)));
typedef float    f32x16 __attribute__((ext_vector_type(16)));
typedef unsigned u32x4  __attribute__((ext_vector_type(4)));
typedef unsigned u32x2  __attribute__((ext_vector_type(2)));

// conv geometry: block = 64 o (one quarter) x 512 px (8 rows), 4 waves
#define RT8   8                    // output rows per block
#define XR    10                   // staged rows (halo)
#define XC    66                   // staged cols (halo)
#define XTILE (XR*2*XC*8)          // 10560 shorts, single buffer (21120 B)
#define WTILE (9*2*64*8)           // 9216 shorts per buffer (18432 B)
#define WORP_PER WTILE             // shorts per (b,cc,oq)
#define WORP_BYTES ((size_t)B_*16*4*WORP_PER*2)   // 18,874,368 B

__device__ __forceinline__ unsigned cvtpk(float lo, float hi) {
    unsigned r;
    asm("v_cvt_pk_bf16_f32 %0, %1, %2" : "=v"(r) : "v"(lo), "v"(hi));
    return r;
}

__device__ __forceinline__ void gload16(const void* g, void* l) {
    __builtin_amdgcn_global_load_lds(
        (const __attribute__((address_space(1))) unsigned int*)g,
        (__attribute__((address_space(3))) unsigned int*)l, 16, 0, 0);
}

// ---------------------------------------------------------------- pool ------
__global__ __launch_bounds__(256) void pool_kernel(const float* __restrict__ x,
                                                   float* __restrict__ pooled) {
    int bc = blockIdx.x;
    const float4* p = (const float4*)(x + (size_t)bc * 4096);
    float s = 0.f;
#pragma unroll
    for (int i = 0; i < 4; ++i) {
        float4 v = p[threadIdx.x + 256 * i];
        s += v.x + v.y + v.z + v.w;
    }
#pragma unroll
    for (int off = 32; off; off >>= 1) s += __shfl_down(s, off, 64);
    __shared__ float red[4];
    int lane = threadIdx.x & 63, wid = threadIdx.x >> 6;
    if (lane == 0) red[wid] = s;
    __syncthreads();
    if (threadIdx.x == 0)
        pooled[bc] = (red[0] + red[1] + red[2] + red[3]) * (1.0f / 4096.0f);
}

// ---------------------------------------------------------------- mix -------
// Produces worp[b][cc][oq][tap][lh][o64][8c] (bf16), byte-for-byte the conv
// LDS w-tile so conv can global_load_lds it linearly. Coeffs computed inline.
__global__ __launch_bounds__(256) void mix_kernel(const float* __restrict__ bank,
                                                  const float* __restrict__ pooled,
                                                  const float* __restrict__ W_fc,
                                                  const float* __restrict__ b_fc,
                                                  short* __restrict__ worp) {
    const int b  = blockIdx.x;
    const int cc = blockIdx.y;
    const int t  = threadIdx.x, lane = t & 63, wid = t >> 6;

    __shared__ float bankL[4 * 64 * 37];   // [k][oc][4c*9 + pad] = 37888 B
    __shared__ float lg[4];

    // ---- routing coeffs (wave w computes logit w)
    {
        float s = 0.f;
#pragma unroll
        for (int q = 0; q < 4; ++q) {
            int c = lane * 4 + q;
            s += pooled[b * C_ + c] * W_fc[wid * C_ + c];
        }
#pragma unroll
        for (int off = 32; off; off >>= 1) s += __shfl_down(s, off, 64);
        if (lane == 0) lg[wid] = s + b_fc[wid];
    }
    __syncthreads();
    float l0 = lg[0], l1 = lg[1], l2 = lg[2], l3 = lg[3];
    float mx = fmaxf(fmaxf(l0, l1), fmaxf(l2, l3));
    float e0 = expf(l0 - mx), e1 = expf(l1 - mx), e2 = expf(l2 - mx), e3 = expf(l3 - mx);
    float inv = 1.f / (e0 + e1 + e2 + e3);
    const float cf0 = e0 * inv, cf1 = e1 * inv, cf2 = e2 * inv, cf3 = e3 * inv;

    const int oq  = t >> 6;    // also rot (o = t)
    const int o64 = t & 63;    // also oc

    for (int sub = 0; sub < 4; ++sub) {          // 4 channels per pass
        __syncthreads();
        // stage bank slice: runs of 36 floats per (k,oc)
        for (int i = t; i < 9216; i += 256) {
            int run = i / 36, e = i % 36;
            bankL[run * 37 + e] = bank[((size_t)run * C_ + cc * 16 + sub * 4) * 9 + e];
        }
        __syncthreads();

        const int lhs = sub >> 1;
        const float* bp = &bankL[o64 * 37];
#pragma unroll
        for (int ti = 0; ti < 3; ++ti)
#pragma unroll
            for (int tj = 0; tj < 3; ++tj) {
                int si, sj;                       // (si,sj) = rot^-1(ti,tj)
                if      (oq == 0) { si = ti;     sj = tj;     }
                else if (oq == 1) { si = tj;     sj = 2 - ti; }
                else if (oq == 2) { si = 2 - ti; sj = 2 - tj; }
                else              { si = 2 - tj; sj = ti;     }
                const int sij = si * 3 + sj;
                float v[4];
#pragma unroll
                for (int c4 = 0; c4 < 4; ++c4) {
                    const float* q = bp + c4 * 9 + sij;
                    v[c4] = cf0 * q[0] + cf1 * q[64 * 37] + cf2 * q[2 * 64 * 37]
                          + cf3 * q[3 * 64 * 37];
                }
                u32x2 d = { cvtpk(v[0], v[1]), cvtpk(v[2], v[3]) };
                size_t base = (((((size_t)(b * 16 + cc) * 4 + oq) * 9 + (ti * 3 + tj)) * 2
                                + lhs) * 64 + o64) * 8 + (sub & 1) * 4;
                *(u32x2*)&worp[base] = d;
            }
    }
}

// ---------------------------------------------------------------- conv ------
// Block: 64 o x 512 px (8 rows); 4 waves each 64o x 128px = 2x2x4 frags of
// 32x32x16.  w double-buffered via global_load_lds; x single-buffered with
// issue-early/write-late split.  LDS layouts are [..][lh][idx][8c] so every
// frag read is 32 lanes x consecutive 16 B (conflict-free, b128-aligned).
__global__ __launch_bounds__(256, 2)
void conv_mfma(const float* __restrict__ x, const short* __restrict__ worp,
               float* __restrict__ out) {
    __shared__ short xls[XTILE];
    __shared__ short wls[2 * WTILE];

    // XCD swizzle: the 4 o-quarter blocks sharing x rows land on one XCD
    const int g    = blockIdx.x;
    const int w    = (g & 7) * 64 + (g >> 3);
    const int oq   = w & 3;
    const int m    = w >> 2;
    const int rowt = m & 7;
    const int b    = m >> 3;
    const int y0   = rowt * RT8;

    const int t    = threadIdx.x;
    const int lane = t & 63;
    const int wid  = t >> 6;                    // px quarter
    const int l31  = lane & 31;
    const int lh   = lane >> 5;

    const float* xb  = x + ((size_t)b << 20);
    const short* wbB = worp + ((size_t)(b * 16) * 4 + oq) * WORP_PER;

    // ---- x staging slot geometry (chunk-independent)
    int  goff[3], lb[3];
    bool act[3], inb[3];
#pragma unroll
    for (int si = 0; si < 3; ++si) {
        int s = t + si * 256;
        act[si] = (s < XR * XC);
        int r = s / XC, col = s % XC;
        int y = y0 + r - 1, gx = col - 1;
        inb[si]  = act[si] && (unsigned)y < 64 && (unsigned)gx < 64;
        goff[si] = y * 64 + gx;
        lb[si]   = ((r * 2) * XC + col) * 8;
    }
    float xf0[16], xf1[16], xf2[16];

#define LOADSLOT(xf, si, ccc)                                                   \
    { const float* p = xb + ((size_t)(ccc) << 16) + goff[si];                   \
      _Pragma("unroll")                                                         \
      for (int ci = 0; ci < 16; ++ci) xf[ci] = inb[si] ? p[(size_t)ci << 12] : 0.f; }

#define WRITESLOT(xf, si)                                                       \
    if (act[si]) {                                                              \
        u32x4 dA = { cvtpk(xf[0], xf[1]),  cvtpk(xf[2], xf[3]),                 \
                     cvtpk(xf[4], xf[5]),  cvtpk(xf[6], xf[7]) };               \
        u32x4 dB = { cvtpk(xf[8], xf[9]),  cvtpk(xf[10], xf[11]),               \
                     cvtpk(xf[12], xf[13]), cvtpk(xf[14], xf[15]) };            \
        *(u32x4*)&xls[lb[si]]          = dA;                                    \
        *(u32x4*)&xls[lb[si] + XC * 8] = dB;                                    \
    }

#define GLOADW(ccc, par)                                                        \
    { const char* wsrc = (const char*)(wbB + (size_t)(ccc) * (4 * WORP_PER));   \
      char* wdst = (char*)(wls + (par) * WTILE);                                \
      for (int u = wid; u < 18; u += 4)                                         \
          gload16(wsrc + u * 1024 + lane * 16, wdst + u * 1024); }

    f32x16 acc0[4] = {}, acc1[4] = {};

    // ---- prologue: stage chunk 0
    GLOADW(0, 0);
    LOADSLOT(xf0, 0, 0); LOADSLOT(xf1, 1, 0); LOADSLOT(xf2, 2, 0);
    WRITESLOT(xf0, 0);   WRITESLOT(xf1, 1);   WRITESLOT(xf2, 2);
    __syncthreads();

    for (int cc = 0; cc < 16; ++cc) {
        const bool pre = (cc < 15);
        if (pre) {
            GLOADW(cc + 1, (cc + 1) & 1);
            LOADSLOT(xf0, 0, cc + 1);
            LOADSLOT(xf1, 1, cc + 1);
            LOADSLOT(xf2, 2, cc + 1);
        }
        // ---- compute chunk cc
        const short* wcur = wls + (cc & 1) * WTILE;
#pragma unroll
        for (int i = 0; i < 3; ++i)
#pragma unroll
            for (int j = 0; j < 3; ++j) {
                const int tap = i * 3 + j;
                const short* wp = wcur + ((tap * 2 + lh) * 64 + l31) * 8;
                bf16x8 A0 = *(const bf16x8*)wp;
                bf16x8 A1 = *(const bf16x8*)(wp + 256);
#pragma unroll
                for (int pf = 0; pf < 4; ++pf) {
                    const int rr   = ((wid * 128 + pf * 32) >> 6) + i;
                    const int colb = ((wid * 128 + pf * 32) & 63) + j;
                    bf16x8 Bv = *(const bf16x8*)&xls[((rr * 2 + lh) * XC + colb + l31) * 8];
                    acc0[pf] = __builtin_amdgcn_mfma_f32_32x32x16_bf16(A0, Bv, acc0[pf], 0, 0, 0);
                    acc1[pf] = __builtin_amdgcn_mfma_f32_32x32x16_bf16(A1, Bv, acc1[pf], 0, 0, 0);
                }
            }
        __syncthreads();               // x reads of chunk cc complete
        if (pre) {
            WRITESLOT(xf0, 0); WRITESLOT(xf1, 1); WRITESLOT(xf2, 2);
        }
        __syncthreads();               // x writes + w gload visible
    }

    // ---- epilogue
#pragma unroll
    for (int pf = 0; pf < 4; ++pf) {
        const int yb  = y0 + 2 * wid + (pf >> 1);
        const int xcb = 32 * (pf & 1) + l31;
#pragma unroll
        for (int r = 0; r < 16; ++r) {
            const int orow = (r & 3) + 8 * (r >> 2) + 4 * lh;
            const int o0   = oq * 64 + orow;
            out[((size_t)(b * O_ + o0)      << 12) + yb * 64 + xcb] = acc0[pf][r];
            out[((size_t)(b * O_ + o0 + 32) << 12) + yb * 64 + xcb] = acc1[pf][r];
        }
    }
#undef LOADSLOT
#undef WRITESLOT
#undef GLOADW
}

// ---------------------------------------------------------------- launch ----
extern "C" void kernel_launch(void* const* d_in, const int* in_sizes, int n_in,
                              void* d_out, int out_size, void* d_ws, size_t ws_size,
                              hipStream_t stream) {
    const float* x    = (const float*)d_in[0];
    const float* W_fc = (const float*)d_in[1];
    const float* b_fc = (const float*)d_in[2];
    const float* bank = (const float*)d_in[3];
    float* out = (float*)d_out;

    short* worp   = (short*)d_ws;
    float* pooled = (float*)((char*)d_ws + WORP_BYTES);

    pool_kernel<<<B_ * C_, 256, 0, stream>>>(x, pooled);
    mix_kernel<<<dim3(B_, 16), 256, 0, stream>>>(bank, pooled, W_fc, b_fc, worp);
    conv_mfma<<<512, 256, 0, stream>>>(x, worp, out);
}

// Round 4
// 112.748 us; speedup vs baseline: 11.0067x; 1.0957x over previous
//
#include <hip/hip_runtime.h>

#define B_  16
#define C_  256
#define O_  256

typedef short    bf16x8 __attribute__((ext_vector_type(8)));
typedef float    f32x16 __attribute__((ext_vector_type(16)));
typedef unsigned u32x4  __attribute__((ext_vector_type(4)));
typedef unsigned u32x2  __attribute__((ext_vector_type(2)));

// xT layout: [b][cc][yphys 0..65][lh 0..1][col 0..65][8c] bf16
//   yphys = logical y + 1; rows 0 and 65 are zero; cols 0 and 65 are zero.
#define XROW_SH  1056                              // shorts per yphys row (2*66*8)
#define XBC_SH   (66 * XROW_SH)                    // 69696 shorts per (b,cc)
#define XT_BYTES ((size_t)B_ * 16 * XBC_SH * 2)    // 35,684,352 B

#define WTILE_SH 9216                              // shorts per (b,cc,oq) w-tile
#define WORP_BYTES ((size_t)B_ * 16 * 4 * WTILE_SH * 2)  // 18,874,368 B

#define XBUF_SH  10752   // LDS x buffer: 21504 B = 21 gload units (window 21120 B)

__device__ __forceinline__ unsigned cvtpk(float lo, float hi) {
    unsigned r;
    asm("v_cvt_pk_bf16_f32 %0, %1, %2" : "=v"(r) : "v"(lo), "v"(hi));
    return r;
}

__device__ __forceinline__ void gload16(const void* g, void* l) {
    __builtin_amdgcn_global_load_lds(
        (const __attribute__((address_space(1))) unsigned int*)g,
        (__attribute__((address_space(3))) unsigned int*)l, 16, 0, 0);
}

// ---------------------------------------------------------------- xprep -----
// fp32 x -> bf16 xT in conv-LDS layout (+ halo zeros) + pooled partial sums.
// grid (cc=16, b=16, z=4); each block: 16 channels x 16 logical y rows.
__global__ __launch_bounds__(256) void xprep_kernel(const float* __restrict__ x,
                                                    short* __restrict__ xT,
                                                    float* __restrict__ pooled4) {
    const int cc = blockIdx.x;
    const int b  = blockIdx.y;
    const int z  = blockIdx.z;
    const int t  = threadIdx.x;

    __shared__ float xsf[2][16][67];

    short* xTb = xT + (size_t)(b * 16 + cc) * XBC_SH;
    const float* xb = x + ((size_t)(b * C_ + cc * 16) << 12);

    // halo zeros: side cols of this z's 16 rows (+ full top/bottom rows for z 0/3)
    {
        u32x4 zv = {0, 0, 0, 0};
        int nz = 64 + ((z == 0 || z == 3) ? 132 : 0);
        for (int i = t; i < nz; i += 256) {
            int off;
            if (i < 64) {
                int row = z * 16 + 1 + (i >> 2);
                int sub = i & 3;
                off = row * XROW_SH + (sub >> 1) * 528 + ((sub & 1) ? 65 * 8 : 0);
            } else {
                off = (z == 0 ? 0 : 65 * XROW_SH) + (i - 64) * 8;
            }
            *(u32x4*)&xTb[off] = zv;
        }
    }

    const int cl = t >> 4;      // channel 0..15
    const int xq = t & 15;      // col quad
    float s = 0.f;

    for (int it = 0; it < 8; ++it) {
        const int ybase = z * 16 + it * 2;
        const float* src = xb + ((size_t)cl << 12) + ybase * 64 + xq * 4;
        float4 v0 = *(const float4*)src;
        float4 v1 = *(const float4*)(src + 64);
        s += v0.x + v0.y + v0.z + v0.w + v1.x + v1.y + v1.z + v1.w;
        __syncthreads();                       // previous iter's readers done
        float* d0 = &xsf[0][cl][xq * 4];
        d0[0] = v0.x; d0[1] = v0.y; d0[2] = v0.z; d0[3] = v0.w;
        float* d1 = &xsf[1][cl][xq * 4];
        d1[0] = v1.x; d1[1] = v1.y; d1[2] = v1.z; d1[3] = v1.w;
        __syncthreads();
        // transpose-write: thread -> (yy, lh, col)
        const int yy  = t >> 7;
        const int lhh = (t >> 6) & 1;
        const int col = (t & 63) + 1;
        const float* rr = &xsf[yy][lhh * 8][col - 1];
        u32x4 d;
        d[0] = cvtpk(rr[0 * 67], rr[1 * 67]);
        d[1] = cvtpk(rr[2 * 67], rr[3 * 67]);
        d[2] = cvtpk(rr[4 * 67], rr[5 * 67]);
        d[3] = cvtpk(rr[6 * 67], rr[7 * 67]);
        *(u32x4*)&xTb[(ybase + yy + 1) * XROW_SH + lhh * 528 + col * 8] = d;
    }

#pragma unroll
    for (int off = 1; off < 16; off <<= 1) s += __shfl_xor(s, off, 64);
    if (xq == 0)
        pooled4[(z * B_ + b) * C_ + cc * 16 + cl] = s * (1.0f / 4096.0f);
}

// ---------------------------------------------------------------- mix -------
// worp[b][cc][oq][tap][lh][o64][8c] bf16 — byte-identical to conv's w LDS tile.
__global__ __launch_bounds__(256) void mix_kernel(const float* __restrict__ bank,
                                                  const float* __restrict__ pooled4,
                                                  const float* __restrict__ W_fc,
                                                  const float* __restrict__ b_fc,
                                                  short* __restrict__ worp) {
    const int b  = blockIdx.x;
    const int cc = blockIdx.y;
    const int t  = threadIdx.x, lane = t & 63, wid = t >> 6;

    __shared__ float bankL[4 * 64 * 37];
    __shared__ float lg[4];

    {
        float s = 0.f;
#pragma unroll
        for (int q = 0; q < 4; ++q) {
            int c = lane * 4 + q;
            float pv = pooled4[b * C_ + c] + pooled4[(B_ + b) * C_ + c]
                     + pooled4[(2 * B_ + b) * C_ + c] + pooled4[(3 * B_ + b) * C_ + c];
            s += pv * W_fc[wid * C_ + c];
        }
#pragma unroll
        for (int off = 32; off; off >>= 1) s += __shfl_down(s, off, 64);
        if (lane == 0) lg[wid] = s + b_fc[wid];
    }
    __syncthreads();
    float l0 = lg[0], l1 = lg[1], l2 = lg[2], l3 = lg[3];
    float mx = fmaxf(fmaxf(l0, l1), fmaxf(l2, l3));
    float e0 = expf(l0 - mx), e1 = expf(l1 - mx), e2 = expf(l2 - mx), e3 = expf(l3 - mx);
    float inv = 1.f / (e0 + e1 + e2 + e3);
    const float cf0 = e0 * inv, cf1 = e1 * inv, cf2 = e2 * inv, cf3 = e3 * inv;

    const int oq  = t >> 6;
    const int o64 = t & 63;

    for (int sub = 0; sub < 4; ++sub) {
        __syncthreads();
        for (int i = t; i < 9216; i += 256) {
            int run = i / 36, e = i % 36;
            bankL[run * 37 + e] = bank[((size_t)run * C_ + cc * 16 + sub * 4) * 9 + e];
        }
        __syncthreads();

        const int lhs = sub >> 1;
        const float* bp = &bankL[o64 * 37];
#pragma unroll
        for (int ti = 0; ti < 3; ++ti)
#pragma unroll
            for (int tj = 0; tj < 3; ++tj) {
                int si, sj;
                if      (oq == 0) { si = ti;     sj = tj;     }
                else if (oq == 1) { si = tj;     sj = 2 - ti; }
                else if (oq == 2) { si = 2 - ti; sj = 2 - tj; }
                else              { si = 2 - tj; sj = ti;     }
                const int sij = si * 3 + sj;
                float v[4];
#pragma unroll
                for (int c4 = 0; c4 < 4; ++c4) {
                    const float* q = bp + c4 * 9 + sij;
                    v[c4] = cf0 * q[0] + cf1 * q[64 * 37] + cf2 * q[2 * 64 * 37]
                          + cf3 * q[3 * 64 * 37];
                }
                u32x2 d = { cvtpk(v[0], v[1]), cvtpk(v[2], v[3]) };
                size_t base = (((((size_t)(b * 16 + cc) * 4 + oq) * 9 + (ti * 3 + tj)) * 2
                                + lhs) * 64 + o64) * 8 + (sub & 1) * 4;
                *(u32x2*)&worp[base] = d;
            }
    }
}

// ---------------------------------------------------------------- conv ------
// Block: 64 o x 512 px (8 rows), 4 waves; both operands staged purely via
// global_load_lds, double-buffered; ONE barrier per K-chunk; setprio on MFMA.
__global__ __launch_bounds__(256, 2)
void conv_mfma(const short* __restrict__ xT, const short* __restrict__ worp,
               float* __restrict__ out) {
    __shared__ short lds[2 * XBUF_SH + 2 * WTILE_SH];   // 79,872 B

    const int g    = blockIdx.x;
    const int w    = (g & 7) * 64 + (g >> 3);   // XCD swizzle (512 = 8*64, bijective)
    const int oq   = w & 3;
    const int m    = w >> 2;
    const int rowt = m & 7;
    const int b    = m >> 3;
    const int y0   = rowt * 8;

    const int t    = threadIdx.x;
    const int lane = t & 63;
    const int wid  = t >> 6;
    const int l31  = lane & 31;
    const int lh   = lane >> 5;

    const char* xsrcB = (const char*)xT
        + ((size_t)(b * 16) * XBC_SH + (size_t)y0 * XROW_SH) * 2 + lane * 16;
    const char* wsrcB = (const char*)worp
        + (((size_t)(b * 16) * 4) + oq) * (WTILE_SH * 2) + lane * 16;

#define STAGE(ccc, p)                                                           \
    { const char* xs = xsrcB + (size_t)(ccc) * (XBC_SH * 2);                    \
      const char* ws = wsrcB + (size_t)(ccc) * (4 * WTILE_SH * 2);              \
      char* xd = (char*)lds + (p) * (XBUF_SH * 2);                              \
      char* wd = (char*)lds + 2 * (XBUF_SH * 2) + (p) * (WTILE_SH * 2);         \
      for (int u = wid; u < 21; u += 4) gload16(xs + u * 1024, xd + u * 1024);  \
      for (int u = wid; u < 18; u += 4) gload16(ws + u * 1024, wd + u * 1024); }

    f32x16 acc0[4] = {}, acc1[4] = {};

    STAGE(0, 0);
    __syncthreads();

    for (int cc = 0; cc < 16; ++cc) {
        const int p = cc & 1;
        if (cc < 15) STAGE(cc + 1, p ^ 1);
        const short* xcur = lds + p * XBUF_SH;
        const short* wcur = lds + 2 * XBUF_SH + p * WTILE_SH;
        __builtin_amdgcn_s_setprio(1);
#pragma unroll
        for (int i = 0; i < 3; ++i)
#pragma unroll
            for (int j = 0; j < 3; ++j) {
                const int tap = i * 3 + j;
                const short* wp = wcur + ((tap * 2 + lh) * 64 + l31) * 8;
                bf16x8 A0 = *(const bf16x8*)wp;
                bf16x8 A1 = *(const bf16x8*)(wp + 256);
#pragma unroll
                for (int pf = 0; pf < 4; ++pf) {
                    const int rl   = 2 * wid + (pf >> 1) + i;        // window row
                    const int colb = (pf & 1) * 32 + j;
                    bf16x8 Bv = *(const bf16x8*)
                        &xcur[((rl * 2 + lh) * 66 + colb + l31) * 8];
                    acc0[pf] = __builtin_amdgcn_mfma_f32_32x32x16_bf16(A0, Bv, acc0[pf], 0, 0, 0);
                    acc1[pf] = __builtin_amdgcn_mfma_f32_32x32x16_bf16(A1, Bv, acc1[pf], 0, 0, 0);
                }
            }
        __builtin_amdgcn_s_setprio(0);
        __syncthreads();
    }
#undef STAGE

#pragma unroll
    for (int pf = 0; pf < 4; ++pf) {
        const int yb  = y0 + 2 * wid + (pf >> 1);
        const int xcb = 32 * (pf & 1) + l31;
#pragma unroll
        for (int r = 0; r < 16; ++r) {
            const int orow = (r & 3) + 8 * (r >> 2) + 4 * lh;
            const int o0   = oq * 64 + orow;
            out[((size_t)(b * O_ + o0)      << 12) + yb * 64 + xcb] = acc0[pf][r];
            out[((size_t)(b * O_ + o0 + 32) << 12) + yb * 64 + xcb] = acc1[pf][r];
        }
    }
}

// ---------------------------------------------------------------- launch ----
extern "C" void kernel_launch(void* const* d_in, const int* in_sizes, int n_in,
                              void* d_out, int out_size, void* d_ws, size_t ws_size,
                              hipStream_t stream) {
    const float* x    = (const float*)d_in[0];
    const float* W_fc = (const float*)d_in[1];
    const float* b_fc = (const float*)d_in[2];
    const float* bank = (const float*)d_in[3];
    float* out = (float*)d_out;

    short* xTb     = (short*)d_ws;
    short* worp    = (short*)((char*)d_ws + XT_BYTES);
    float* pooled4 = (float*)((char*)d_ws + XT_BYTES + WORP_BYTES);

    xprep_kernel<<<dim3(16, 16, 4), 256, 0, stream>>>(x, xTb, pooled4);
    mix_kernel<<<dim3(B_, 16), 256, 0, stream>>>(bank, pooled4, W_fc, b_fc, worp);
    conv_mfma<<<512, 256, 0, stream>>>(xTb, worp, out);
}

// Round 5
// 111.109 us; speedup vs baseline: 11.1691x; 1.0148x over previous
//
#include <hip/hip_runtime.h>

#define B_  16
#define C_  256
#define O_  256

typedef short    bf16x8 __attribute__((ext_vector_type(8)));
typedef float    f32x16 __attribute__((ext_vector_type(16)));
typedef unsigned u32x4  __attribute__((ext_vector_type(4)));
typedef unsigned u32x2  __attribute__((ext_vector_type(2)));

// xT layout: [b][cc][yphys 0..65][lh 0..1][col 0..65][8c] bf16
#define XROW_SH  1056
#define XBC_SH   (66 * XROW_SH)
#define XT_BYTES ((size_t)B_ * 16 * XBC_SH * 2)

#define WTILE_SH 9216
#define WORP_BYTES ((size_t)B_ * 16 * 4 * WTILE_SH * 2)

#define XBUF_SH  10752

__device__ __forceinline__ unsigned cvtpk(float lo, float hi) {
    unsigned r;
    asm("v_cvt_pk_bf16_f32 %0, %1, %2" : "=v"(r) : "v"(lo), "v"(hi));
    return r;
}

__device__ __forceinline__ void gload16(const void* g, void* l) {
    __builtin_amdgcn_global_load_lds(
        (const __attribute__((address_space(1))) unsigned int*)g,
        (__attribute__((address_space(3))) unsigned int*)l, 16, 0, 0);
}

// ---------------------------------------------------------------- xprep -----
__global__ __launch_bounds__(256) void xprep_kernel(const float* __restrict__ x,
                                                    short* __restrict__ xT,
                                                    float* __restrict__ pooled4) {
    const int cc = blockIdx.x;
    const int b  = blockIdx.y;
    const int z  = blockIdx.z;
    const int t  = threadIdx.x;

    __shared__ float xsf[2][2][16][67];        // [buf][row-pair][c][col]

    short* xTb = xT + (size_t)(b * 16 + cc) * XBC_SH;
    const float* xb = x + ((size_t)(b * C_ + cc * 16) << 12);

    {   // halo zeros
        u32x4 zv = {0, 0, 0, 0};
        int nz = 64 + ((z == 0 || z == 3) ? 132 : 0);
        for (int i = t; i < nz; i += 256) {
            int off;
            if (i < 64) {
                int row = z * 16 + 1 + (i >> 2);
                int sub = i & 3;
                off = row * XROW_SH + (sub >> 1) * 528 + ((sub & 1) ? 65 * 8 : 0);
            } else {
                off = (z == 0 ? 0 : 65 * XROW_SH) + (i - 64) * 8;
            }
            *(u32x4*)&xTb[off] = zv;
        }
    }

    const int cl = t >> 4;
    const int xq = t & 15;
    const int yy  = t >> 7;
    const int lhh = (t >> 6) & 1;
    const int col = (t & 63) + 1;
    float s = 0.f;

    for (int it = 0; it < 8; ++it) {
        const int bufi  = it & 1;
        const int ybase = z * 16 + it * 2;
        const float* src = xb + ((size_t)cl << 12) + ybase * 64 + xq * 4;
        float4 v0 = *(const float4*)src;
        float4 v1 = *(const float4*)(src + 64);
        s += v0.x + v0.y + v0.z + v0.w + v1.x + v1.y + v1.z + v1.w;
        float* d0 = &xsf[bufi][0][cl][xq * 4];
        d0[0] = v0.x; d0[1] = v0.y; d0[2] = v0.z; d0[3] = v0.w;
        float* d1 = &xsf[bufi][1][cl][xq * 4];
        d1[0] = v1.x; d1[1] = v1.y; d1[2] = v1.z; d1[3] = v1.w;
        __syncthreads();
        const float* rr = &xsf[bufi][yy][lhh * 8][col - 1];
        u32x4 d;
        d[0] = cvtpk(rr[0 * 67], rr[1 * 67]);
        d[1] = cvtpk(rr[2 * 67], rr[3 * 67]);
        d[2] = cvtpk(rr[4 * 67], rr[5 * 67]);
        d[3] = cvtpk(rr[6 * 67], rr[7 * 67]);
        *(u32x4*)&xTb[(ybase + yy + 1) * XROW_SH + lhh * 528 + col * 8] = d;
    }

#pragma unroll
    for (int off = 1; off < 16; off <<= 1) s += __shfl_xor(s, off, 64);
    if (xq == 0)
        pooled4[(z * B_ + b) * C_ + cc * 16 + cl] = s * (1.0f / 4096.0f);
}

// ---------------------------------------------------------------- mix -------
__global__ __launch_bounds__(256) void mix_kernel(const float* __restrict__ bank,
                                                  const float* __restrict__ pooled4,
                                                  const float* __restrict__ W_fc,
                                                  const float* __restrict__ b_fc,
                                                  short* __restrict__ worp) {
    const int b  = blockIdx.x;
    const int cc = blockIdx.y;
    const int t  = threadIdx.x, lane = t & 63, wid = t >> 6;

    __shared__ float bankL[4 * 64 * 37];
    __shared__ float lg[4];

    {
        float s = 0.f;
#pragma unroll
        for (int q = 0; q < 4; ++q) {
            int c = lane * 4 + q;
            float pv = pooled4[b * C_ + c] + pooled4[(B_ + b) * C_ + c]
                     + pooled4[(2 * B_ + b) * C_ + c] + pooled4[(3 * B_ + b) * C_ + c];
            s += pv * W_fc[wid * C_ + c];
        }
#pragma unroll
        for (int off = 32; off; off >>= 1) s += __shfl_down(s, off, 64);
        if (lane == 0) lg[wid] = s + b_fc[wid];
    }
    __syncthreads();
    float l0 = lg[0], l1 = lg[1], l2 = lg[2], l3 = lg[3];
    float mx = fmaxf(fmaxf(l0, l1), fmaxf(l2, l3));
    float e0 = expf(l0 - mx), e1 = expf(l1 - mx), e2 = expf(l2 - mx), e3 = expf(l3 - mx);
    float inv = 1.f / (e0 + e1 + e2 + e3);
    const float cf0 = e0 * inv, cf1 = e1 * inv, cf2 = e2 * inv, cf3 = e3 * inv;

    const int oq  = t >> 6;
    const int o64 = t & 63;

    for (int sub = 0; sub < 4; ++sub) {
        __syncthreads();
        for (int i = t; i < 9216; i += 256) {
            int run = i / 36, e = i % 36;
            bankL[run * 37 + e] = bank[((size_t)run * C_ + cc * 16 + sub * 4) * 9 + e];
        }
        __syncthreads();

        const int lhs = sub >> 1;
        const float* bp = &bankL[o64 * 37];
#pragma unroll
        for (int ti = 0; ti < 3; ++ti)
#pragma unroll
            for (int tj = 0; tj < 3; ++tj) {
                int si, sj;
                if      (oq == 0) { si = ti;     sj = tj;     }
                else if (oq == 1) { si = tj;     sj = 2 - ti; }
                else if (oq == 2) { si = 2 - ti; sj = 2 - tj; }
                else              { si = 2 - tj; sj = ti;     }
                const int sij = si * 3 + sj;
                float v[4];
#pragma unroll
                for (int c4 = 0; c4 < 4; ++c4) {
                    const float* q = bp + c4 * 9 + sij;
                    v[c4] = cf0 * q[0] + cf1 * q[64 * 37] + cf2 * q[2 * 64 * 37]
                          + cf3 * q[3 * 64 * 37];
                }
                u32x2 d = { cvtpk(v[0], v[1]), cvtpk(v[2], v[3]) };
                size_t base = (((((size_t)(b * 16 + cc) * 4 + oq) * 9 + (ti * 3 + tj)) * 2
                                + lhs) * 64 + o64) * 8 + (sub & 1) * 4;
                *(u32x2*)&worp[base] = d;
            }
    }
}

// ---------------------------------------------------------------- conv ------
// 64 o x 512 px per block, 4 waves; gload_lds double-buffer, 1 barrier/chunk;
// B-fragments register-cached across tap-rows (24 LDS reads instead of 36).
__global__ __launch_bounds__(256, 2)
void conv_mfma(const short* __restrict__ xT, const short* __restrict__ worp,
               float* __restrict__ out) {
    __shared__ short lds[2 * XBUF_SH + 2 * WTILE_SH];

    const int g    = blockIdx.x;
    const int w    = (g & 7) * 64 + (g >> 3);
    const int oq   = w & 3;
    const int m    = w >> 2;
    const int rowt = m & 7;
    const int b    = m >> 3;
    const int y0   = rowt * 8;

    const int t    = threadIdx.x;
    const int lane = t & 63;
    const int wid  = t >> 6;
    const int l31  = lane & 31;
    const int lh   = lane >> 5;

    const char* xsrcB = (const char*)xT
        + ((size_t)(b * 16) * XBC_SH + (size_t)y0 * XROW_SH) * 2 + lane * 16;
    const char* wsrcB = (const char*)worp
        + (((size_t)(b * 16) * 4) + oq) * (WTILE_SH * 2) + lane * 16;

#define STAGE(ccc, p)                                                           \
    { const char* xs = xsrcB + (size_t)(ccc) * (XBC_SH * 2);                    \
      const char* ws = wsrcB + (size_t)(ccc) * (4 * WTILE_SH * 2);              \
      char* xd = (char*)lds + (p) * (XBUF_SH * 2);                              \
      char* wd = (char*)lds + 2 * (XBUF_SH * 2) + (p) * (WTILE_SH * 2);         \
      for (int u = wid; u < 21; u += 4) gload16(xs + u * 1024, xd + u * 1024);  \
      for (int u = wid; u < 18; u += 4) gload16(ws + u * 1024, wd + u * 1024); }

    // B-frag read: window row r, col shift s
#define BRD(r, s) (*(const bf16x8*)&xcur[(((r) * 2 + lh) * 66 + (s) + l31) * 8])
#define LOADROW(R, r)                                                           \
    { R[0] = BRD(r, 0);  R[1] = BRD(r, 1);  R[2] = BRD(r, 2);                   \
      R[3] = BRD(r, 32); R[4] = BRD(r, 33); R[5] = BRD(r, 34); }

    // tap-row i: RA = row (2wid+i) frags (pf 0,1), RB = row (2wid+i+1) (pf 2,3)
#define TAPROW(i, RA, RB)                                                       \
    _Pragma("unroll")                                                           \
    for (int j = 0; j < 3; ++j) {                                               \
        const int tap = (i) * 3 + j;                                            \
        const short* wp = wcur + ((tap * 2 + lh) * 64 + l31) * 8;               \
        bf16x8 A0 = *(const bf16x8*)wp;                                         \
        bf16x8 A1 = *(const bf16x8*)(wp + 256);                                 \
        acc0[0] = __builtin_amdgcn_mfma_f32_32x32x16_bf16(A0, RA[j],     acc0[0], 0, 0, 0); \
        acc1[0] = __builtin_amdgcn_mfma_f32_32x32x16_bf16(A1, RA[j],     acc1[0], 0, 0, 0); \
        acc0[1] = __builtin_amdgcn_mfma_f32_32x32x16_bf16(A0, RA[3 + j], acc0[1], 0, 0, 0); \
        acc1[1] = __builtin_amdgcn_mfma_f32_32x32x16_bf16(A1, RA[3 + j], acc1[1], 0, 0, 0); \
        acc0[2] = __builtin_amdgcn_mfma_f32_32x32x16_bf16(A0, RB[j],     acc0[2], 0, 0, 0); \
        acc1[2] = __builtin_amdgcn_mfma_f32_32x32x16_bf16(A1, RB[j],     acc1[2], 0, 0, 0); \
        acc0[3] = __builtin_amdgcn_mfma_f32_32x32x16_bf16(A0, RB[3 + j], acc0[3], 0, 0, 0); \
        acc1[3] = __builtin_amdgcn_mfma_f32_32x32x16_bf16(A1, RB[3 + j], acc1[3], 0, 0, 0); \
    }

    f32x16 acc0[4] = {}, acc1[4] = {};

    STAGE(0, 0);
    __syncthreads();

    for (int cc = 0; cc < 16; ++cc) {
        const int p = cc & 1;
        if (cc < 15) STAGE(cc + 1, p ^ 1);
        const short* xcur = lds + p * XBUF_SH;
        const short* wcur = lds + 2 * XBUF_SH + p * WTILE_SH;

        bf16x8 R0[6], R1[6];
        __builtin_amdgcn_s_setprio(1);
        LOADROW(R0, 2 * wid);
        LOADROW(R1, 2 * wid + 1);
        TAPROW(0, R0, R1)
        LOADROW(R0, 2 * wid + 2)            // overwrite oldest row
        TAPROW(1, R1, R0)
        LOADROW(R1, 2 * wid + 3)
        TAPROW(2, R0, R1)
        __builtin_amdgcn_s_setprio(0);
        __syncthreads();
    }
#undef STAGE
#undef BRD
#undef LOADROW
#undef TAPROW

#pragma unroll
    for (int pf = 0; pf < 4; ++pf) {
        const int yb  = y0 + 2 * wid + (pf >> 1);
        const int xcb = 32 * (pf & 1) + l31;
#pragma unroll
        for (int r = 0; r < 16; ++r) {
            const int orow = (r & 3) + 8 * (r >> 2) + 4 * lh;
            const int o0   = oq * 64 + orow;
            __builtin_nontemporal_store(acc0[pf][r],
                &out[((size_t)(b * O_ + o0)      << 12) + yb * 64 + xcb]);
            __builtin_nontemporal_store(acc1[pf][r],
                &out[((size_t)(b * O_ + o0 + 32) << 12) + yb * 64 + xcb]);
        }
    }
}

// ---------------------------------------------------------------- launch ----
extern "C" void kernel_launch(void* const* d_in, const int* in_sizes, int n_in,
                              void* d_out, int out_size, void* d_ws, size_t ws_size,
                              hipStream_t stream) {
    const float* x    = (const float*)d_in[0];
    const float* W_fc = (const float*)d_in[1];
    const float* b_fc = (const float*)d_in[2];
    const float* bank = (const float*)d_in[3];
    float* out = (float*)d_out;

    short* xTb     = (short*)d_ws;
    short* worp    = (short*)((char*)d_ws + XT_BYTES);
    float* pooled4 = (float*)((char*)d_ws + XT_BYTES + WORP_BYTES);

    xprep_kernel<<<dim3(16, 16, 4), 256, 0, stream>>>(x, xTb, pooled4);
    mix_kernel<<<dim3(B_, 16), 256, 0, stream>>>(bank, pooled4, W_fc, b_fc, worp);
    conv_mfma<<<512, 256, 0, stream>>>(xTb, worp, out);
}